// Round 6
// baseline (749.423 us; speedup 1.0000x reference)
//
#include <hip/hip_runtime.h>

typedef float v2f __attribute__((ext_vector_type(2)));
typedef float v4f __attribute__((ext_vector_type(4)));

#define T_STEPS 2048
#define BATCH   2
#define IDIM    40
#define HDIM    44
#define GDIM    176      // 4*H
#define ADIM    262144
#define EDIM    88       // 2*H
#define NCOL    (BATCH * GDIM)   // 352 columns of xproj

__device__ __forceinline__ float fast_sigmoid(float x) {
    return __builtin_amdgcn_rcpf(1.0f + __expf(-x));
}
__device__ __forceinline__ float fast_tanh(float x) {
    // tanh(x) = 1 - 2/(exp(2x)+1); saturates correctly
    return 1.0f - 2.0f * __builtin_amdgcn_rcpf(__expf(2.0f * x) + 1.0f);
}

// K1: xproj[t][b][gi] = b_ih[gi] + b_hh[gi] + sum_i x[t][b][i] * W_ih[gi][i]
__global__ __launch_bounds__(192) void xproj_kernel(
    const float* __restrict__ x,      // [T][B][40]
    const float* __restrict__ W_ih,   // [176][40]
    const float* __restrict__ b_ih,   // [176]
    const float* __restrict__ b_hh,   // [176]
    float* __restrict__ xproj)        // [T][B][176]
{
    const int tb = blockIdx.x;        // t*B + b
    const int gi = threadIdx.x;
    __shared__ __align__(16) float xs[IDIM];
    if (threadIdx.x < IDIM) xs[threadIdx.x] = x[(size_t)tb * IDIM + threadIdx.x];
    __syncthreads();
    if (gi < GDIM) {
        const float* wr = W_ih + gi * IDIM;
        float a0 = 0.f, a1 = 0.f;
        #pragma unroll
        for (int i = 0; i < IDIM; i += 4) {
            float4 wv = *(const float4*)&wr[i];
            float4 xv = *(const float4*)&xs[i];
            a0 += wv.x * xv.x + wv.z * xv.z;
            a1 += wv.y * xv.y + wv.w * xv.w;
        }
        xproj[(size_t)tb * GDIM + gi] = a0 + a1 + b_ih[gi] + b_hh[gi];
    }
}

// K1b: transpose [T][352] -> [352][T] so each lstm lane reads contiguous-in-t
// streams (enables float4-per-4-steps loads with deep prefetch).
__global__ __launch_bounds__(256) void transpose_kernel(
    const float* __restrict__ in,   // [2048][352]
    float* __restrict__ out)        // [352][2048]
{
    __shared__ float tile[32][33];
    const int c0 = blockIdx.x * 32;   // 352 = 11*32 exactly
    const int t0 = blockIdx.y * 32;
    const int lx = threadIdx.x;       // 0..31
    const int ly = threadIdx.y;       // 0..7
    #pragma unroll
    for (int i = 0; i < 32; i += 8)
        tile[ly + i][lx] = in[(size_t)(t0 + ly + i) * NCOL + c0 + lx];
    __syncthreads();
    #pragma unroll
    for (int i = 0; i < 32; i += 8)
        out[(size_t)(c0 + ly + i) * T_STEPS + t0 + lx] = tile[lx][ly + i];
}

// K2: serial LSTM, ONE WAVE per batch. Lane j owns h[j], c[j] and gate rows
// {j, 44+j, 88+j, 132+j} of W_hh in registers. h broadcast via LDS.
// xproj consumed from the TRANSPOSED layout: per gate, one float4 covers 4
// steps; double-buffered 2 groups (8 steps, ~2000+ cyc) ahead of use so the
// ~900-cyc HBM latency is fully hidden (round-4 counters showed the wave
// stalled ~84% of cycles; xproj vmcnt wait was the largest identified chunk).
__global__ __launch_bounds__(64)
__attribute__((amdgpu_waves_per_eu(1, 1)))
void lstm_kernel(
    const float* __restrict__ xt,     // [B][176][T] transposed xproj
    const float* __restrict__ h0,     // [1][B][44]
    const float* __restrict__ c0,     // [1][B][44]
    const float* __restrict__ W_hh,   // [176][44]
    const float* __restrict__ W_v,    // [1][128]
    const float* __restrict__ b_v,    // [1]
    float* __restrict__ base_out)     // [B]
{
    const int b = blockIdx.x;
    const int j = threadIdx.x;          // 0..63; lanes >= 44 are passengers
    const int jj = (j < HDIM) ? j : (HDIM - 1);   // clamped (no OOB)

    __shared__ __align__(16) float h_sh[HDIM];

    // Per-lane weight rows in registers (4 x 44 = 176 floats as 88 v2f pairs)
    v2f wi[22], wf[22], wg[22], wo[22];
    {
        const float* ri = W_hh + (size_t)jj * HDIM;
        const float* rf = W_hh + (size_t)(HDIM + jj) * HDIM;
        const float* rg = W_hh + (size_t)(2 * HDIM + jj) * HDIM;
        const float* ro = W_hh + (size_t)(3 * HDIM + jj) * HDIM;
        #pragma unroll
        for (int k = 0; k < 22; ++k) {
            wi[k] = ((const v2f*)ri)[k];
            wf[k] = ((const v2f*)rf)[k];
            wg[k] = ((const v2f*)rg)[k];
            wo[k] = ((const v2f*)ro)[k];
        }
    }

    float c = c0[b * HDIM + jj];
    if (j < HDIM) h_sh[j] = h0[b * HDIM + j];
    __syncthreads();

    // broadcast-read full h into registers (all lanes)
    v2f hp[22];
    #pragma unroll
    for (int k = 0; k < 11; ++k) {
        v4f t = ((const v4f*)h_sh)[k];
        hp[2 * k]     = __builtin_shufflevector(t, t, 0, 1);
        hp[2 * k + 1] = __builtin_shufflevector(t, t, 2, 3);
    }

    // per-lane gate-input streams, contiguous in t
    const float* si_ = xt + ((size_t)b * GDIM + jj) * T_STEPS;
    const float* sf_ = si_ + (size_t)HDIM * T_STEPS;
    const float* sg_ = si_ + (size_t)(2 * HDIM) * T_STEPS;
    const float* so_ = si_ + (size_t)(3 * HDIM) * T_STEPS;

    // group = 4 steps. cur = ready data, nxt = in flight (1 group ahead);
    // loads for group g+2 issue at end of group g.
    v4f ci = *(const v4f*)(si_ + 0), cf = *(const v4f*)(sf_ + 0);
    v4f cg = *(const v4f*)(sg_ + 0), co = *(const v4f*)(so_ + 0);
    v4f ni = *(const v4f*)(si_ + 4), nf = *(const v4f*)(sf_ + 4);
    v4f ng = *(const v4f*)(sg_ + 4), no = *(const v4f*)(so_ + 4);

    float hval = 0.f;

    #pragma unroll 1
    for (int grp = 0; grp < T_STEPS / 4; ++grp) {
        #pragma unroll
        for (int s = 0; s < 4; ++s) {
            // 4 gate dot-products, one packed accumulator chain per gate
            v2f ai = (v2f)(0.f), af = (v2f)(0.f), ag = (v2f)(0.f), ao = (v2f)(0.f);
            #pragma unroll
            for (int k = 0; k < 22; ++k) {
                ai = __builtin_elementwise_fma(wi[k], hp[k], ai);
                af = __builtin_elementwise_fma(wf[k], hp[k], af);
                ag = __builtin_elementwise_fma(wg[k], hp[k], ag);
                ao = __builtin_elementwise_fma(wo[k], hp[k], ao);
            }
            float gi = ai.x + ai.y + ci[s];
            float gf = af.x + af.y + cf[s];
            float gg = ag.x + ag.y + cg[s];
            float go = ao.x + ao.y + co[s];

            float s_i = fast_sigmoid(gi);
            float s_f = fast_sigmoid(gf);
            float s_o = fast_sigmoid(go);
            float t_g = fast_tanh(gg);
            c = s_f * c + s_i * t_g;
            hval = s_o * fast_tanh(c);

            if (j < HDIM) h_sh[j] = hval;
            __syncthreads();

            #pragma unroll
            for (int k = 0; k < 11; ++k) {
                v4f t = ((const v4f*)h_sh)[k];
                hp[2 * k]     = __builtin_shufflevector(t, t, 0, 1);
                hp[2 * k + 1] = __builtin_shufflevector(t, t, 2, 3);
            }
        }
        // rotate buffers (vmcnt wait lands here, ~2 groups after issue)
        ci = ni; cf = nf; cg = ng; co = no;
        const int g2 = (grp + 2 < T_STEPS / 4) ? (grp + 2) : (T_STEPS / 4 - 1);
        ni = *(const v4f*)(si_ + 4 * g2);
        nf = *(const v4f*)(sf_ + 4 * g2);
        ng = *(const v4f*)(sg_ + 4 * g2);
        no = *(const v4f*)(so_ + 4 * g2);
    }

    // epilogue: base[b] = sum_j h[j]*Wv[j] + c[j]*Wv[44+j] + b_v
    float p = 0.f;
    if (j < HDIM) p = hval * W_v[j] + c * W_v[HDIM + j];
    #pragma unroll
    for (int off = 32; off; off >>= 1) p += __shfl_down(p, off);
    if (j == 0) base_out[b] = p + b_v[0];
}

// K3: out[b][a] = (a < len[b]) ? base[b] + action[b][a][:].w_a : 0
__global__ __launch_bounds__(256) void action_kernel(
    const float* __restrict__ action,     // [B][A][40]
    const int*   __restrict__ act_length, // [B]
    const float* __restrict__ W_v,        // [1][128]; w_a = W_v[88..127]
    const float* __restrict__ base,       // [B]
    float* __restrict__ out)              // [B][A]
{
    const int idx = blockIdx.x * 256 + threadIdx.x;   // 0 .. B*A-1
    const int b = idx >> 18;                          // A = 2^18
    const int a = idx & (ADIM - 1);
    if (a >= act_length[b]) { out[idx] = 0.f; return; }
    const float* row = action + (size_t)idx * IDIM;
    float a0 = 0.f, a1 = 0.f;
    #pragma unroll
    for (int i = 0; i < IDIM; i += 4) {
        float4 av = *(const float4*)&row[i];
        a0 += av.x * W_v[EDIM + i + 0] + av.z * W_v[EDIM + i + 2];
        a1 += av.y * W_v[EDIM + i + 1] + av.w * W_v[EDIM + i + 3];
    }
    out[idx] = base[b] + a0 + a1;
}

extern "C" void kernel_launch(void* const* d_in, const int* in_sizes, int n_in,
                              void* d_out, int out_size, void* d_ws, size_t ws_size,
                              hipStream_t stream) {
    const float* x        = (const float*)d_in[0];
    const float* h0       = (const float*)d_in[1];
    const float* c0       = (const float*)d_in[2];
    const float* action   = (const float*)d_in[3];
    const int*   act_len  = (const int*)  d_in[4];
    const float* W_ih     = (const float*)d_in[5];
    const float* W_hh     = (const float*)d_in[6];
    const float* b_ih     = (const float*)d_in[7];
    const float* b_hh     = (const float*)d_in[8];
    const float* W_v      = (const float*)d_in[9];
    const float* b_v      = (const float*)d_in[10];
    float* out = (float*)d_out;

    float* xproj = (float*)d_ws;                                   // [T][B][176]
    float* xt    = xproj + (size_t)T_STEPS * NCOL;                 // [352][T]
    float* base  = xt + (size_t)NCOL * T_STEPS;                    // B floats

    xproj_kernel<<<dim3(T_STEPS * BATCH), dim3(192), 0, stream>>>(
        x, W_ih, b_ih, b_hh, xproj);
    transpose_kernel<<<dim3(NCOL / 32, T_STEPS / 32), dim3(32, 8), 0, stream>>>(
        xproj, xt);
    lstm_kernel<<<dim3(BATCH), dim3(64), 0, stream>>>(
        xt, h0, c0, W_hh, W_v, b_v, base);
    action_kernel<<<dim3((BATCH * ADIM) / 256), dim3(256), 0, stream>>>(
        action, act_len, W_v, base, out);
}